// Round 10
// baseline (235.250 us; speedup 1.0000x reference)
//
#include <hip/hip_runtime.h>
#include <hip/hip_bf16.h>
#include <math.h>

#define N_NODES 100000
#define N_EDGES 800000
#define IN_C 96
#define OUT_C 64
#define C4 (IN_C / 4)   // 24 float4 chunks per node
#define XPAD 104        // padded LDS row stride in bf16 elems
#define SCAN_B 512      // scan block width

typedef __attribute__((ext_vector_type(8))) short bf16x8;
typedef __attribute__((ext_vector_type(4))) float f32x4;

// bf16 helpers (manual, deterministic RNE)
__device__ __forceinline__ unsigned short f2bf(float f) {
    unsigned u = __float_as_uint(f);
    unsigned r = 0x7FFFu + ((u >> 16) & 1u);
    return (unsigned short)((u + r) >> 16);
}
__device__ __forceinline__ unsigned pack2bf(float a, float b) {
    return (unsigned)f2bf(a) | ((unsigned)f2bf(b) << 16);
}
// packed csr entry: [src:17][dinv_src_bf15:15]  (dinv in (0,1] so sign bit 0)
__device__ __forceinline__ float dec_w(unsigned p) {
    return __uint_as_float((p & 0x7FFFu) << 16);
}
__device__ __forceinline__ float lo_bf(unsigned v) { return __uint_as_float(v << 16); }
__device__ __forceinline__ float hi_bf(unsigned v) { return __uint_as_float(v & 0xFFFF0000u); }

// ================= CSR build =================

// count in-degree AND record each edge's within-node slot (the atomic's return
// value) so the fill pass needs no second atomic. Also zeroes the 16 csr tail
// entries [e, e+16) so gather can load csr unpredicated.
__global__ void count_kernel(const int* __restrict__ col, int* __restrict__ cnt,
                             unsigned short* __restrict__ eidx,
                             unsigned* __restrict__ csr, int e) {
    int i = blockIdx.x * blockDim.x + threadIdx.x;
    if (i < 16) csr[e + i] = 0u;
    if (i < e) {
        int idx = atomicAdd(&cnt[col[i]], 1);
        eidx[i] = (unsigned short)idx;
    }
}

// per-512-block sums
__global__ void scan_pass1_kernel(const int* __restrict__ cnt, int* __restrict__ partials, int n) {
    __shared__ int s[SCAN_B];
    int i = blockIdx.x * SCAN_B + threadIdx.x;
    int v = (i < n) ? cnt[i] : 0;
    s[threadIdx.x] = v;
    __syncthreads();
    for (int off = SCAN_B / 2; off > 0; off >>= 1) {
        if (threadIdx.x < off) s[threadIdx.x] += s[threadIdx.x + off];
        __syncthreads();
    }
    if (threadIdx.x == 0) partials[blockIdx.x] = s[0];
}

// fused scan2+scan3: every block redundantly scans the partials (nparts<=512),
// then scans its own 512 cnt elements; writes row_start/dinv (+total).
__global__ void scan23_kernel(const int* __restrict__ cnt, const int* __restrict__ partials,
                              int* __restrict__ row_start, float* __restrict__ dinv,
                              int n, int nparts) {
    __shared__ int ps[SCAN_B];
    __shared__ int es[SCAN_B];
    int t = threadIdx.x;

    int pv = (t < nparts) ? partials[t] : 0;
    ps[t] = pv;
    __syncthreads();
    int run = pv;
    for (int off = 1; off < SCAN_B; off <<= 1) {
        int tmp = (t >= off) ? ps[t - off] : 0;
        __syncthreads();
        run += tmp;
        ps[t] = run;
        __syncthreads();
    }
    int total = ps[nparts - 1];
    __syncthreads();
    ps[t] = run - pv;   // exclusive
    __syncthreads();
    int block_off = ps[blockIdx.x];

    int i = blockIdx.x * SCAN_B + t;
    int v = (i < n) ? cnt[i] : 0;
    es[t] = v;
    __syncthreads();
    int erun = v;
    for (int off = 1; off < SCAN_B; off <<= 1) {
        int tmp = (t >= off) ? es[t - off] : 0;
        __syncthreads();
        erun += tmp;
        es[t] = erun;
        __syncthreads();
    }
    if (i < n) {
        int start = block_off + erun - v;   // exclusive
        row_start[i] = start;
        dinv[i] = rsqrtf((float)v + 1.0f);
    }
    if (blockIdx.x == 0 && t == 0) row_start[n] = total;
}

// ================= fused: csr_fill + linear, interleaved 2:1 =================
// blockIdx%3 in {0,1} -> fill block (atomic-free: pos = row_start[c]+eidx[i]).
//   Entry stores dinv[src] only (gather multiplies by dinv[dst]) -> one fewer
//   random load per edge than storing the product.
// blockIdx%3 == 2     -> linear block (MFMA x@W^T, W staged in LDS, x loaded
//                        global->reg directly: only 13.3KB LDS -> 8 blocks/CU).

__global__ void fill_linear_kernel(const int* __restrict__ row, const int* __restrict__ col,
                                   const float* __restrict__ dinv,
                                   const int* __restrict__ row_start,
                                   const unsigned short* __restrict__ eidx,
                                   unsigned* __restrict__ csr, int e,
                                   const float* __restrict__ x, const float* __restrict__ W,
                                   unsigned short* __restrict__ y, int n, int nb_lin) {
    __shared__ unsigned short wbf[64 * XPAD];

    int g = blockIdx.x / 3;
    int r3 = blockIdx.x - g * 3;
    if (r3 != 2) {
        int i = (g * 2 + r3) * 256 + threadIdx.x;
        if (i < e) {
            int r = row[i];
            int c = col[i];
            int pos = row_start[c] + (int)eidx[i];
            csr[pos] = ((unsigned)r << 15) | (unsigned)f2bf(dinv[r]);
        }
        return;
    }
    if (g >= nb_lin) return;

    int tid = threadIdx.x;
    int lane = tid & 63;
    int wv = tid >> 6;
    int node0 = g * 64;

    // stage W only (13.3KB)
    for (int i = tid; i < 64 * C4; i += 256) {
        int o = i / C4;
        int c4 = i - o * C4;
        float4 v = ((const float4*)(W + (size_t)o * IN_C))[c4];
        uint2 pk;
        pk.x = pack2bf(v.x, v.y);
        pk.y = pack2bf(v.z, v.w);
        *(uint2*)&wbf[o * XPAD + c4 * 4] = pk;
    }
    __syncthreads();

    int l16 = lane & 15;
    int quad = lane >> 4;

    // A-row for this lane: loaded straight from global (f32 -> bf16, same RNE)
    int arow = node0 + wv * 16 + l16;
    const float* xr = x + (size_t)((arow < n) ? arow : 0) * IN_C + quad * 8;

    f32x4 acc0 = {0.f, 0.f, 0.f, 0.f};
    f32x4 acc1 = {0.f, 0.f, 0.f, 0.f};
    f32x4 acc2 = {0.f, 0.f, 0.f, 0.f};
    f32x4 acc3 = {0.f, 0.f, 0.f, 0.f};

#pragma unroll
    for (int kc = 0; kc < 3; ++kc) {
        float4 v0 = ((const float4*)(xr + kc * 32))[0];
        float4 v1 = ((const float4*)(xr + kc * 32))[1];
        union { bf16x8 v; unsigned u[4]; } au;
        au.u[0] = pack2bf(v0.x, v0.y);
        au.u[1] = pack2bf(v0.z, v0.w);
        au.u[2] = pack2bf(v1.x, v1.y);
        au.u[3] = pack2bf(v1.z, v1.w);
        bf16x8 a = au.v;
        bf16x8 b0 = *(const bf16x8*)&wbf[(0 * 16 + l16) * XPAD + kc * 32 + quad * 8];
        bf16x8 b1 = *(const bf16x8*)&wbf[(1 * 16 + l16) * XPAD + kc * 32 + quad * 8];
        bf16x8 b2 = *(const bf16x8*)&wbf[(2 * 16 + l16) * XPAD + kc * 32 + quad * 8];
        bf16x8 b3 = *(const bf16x8*)&wbf[(3 * 16 + l16) * XPAD + kc * 32 + quad * 8];
        acc0 = __builtin_amdgcn_mfma_f32_16x16x32_bf16(a, b0, acc0, 0, 0, 0);
        acc1 = __builtin_amdgcn_mfma_f32_16x16x32_bf16(a, b1, acc1, 0, 0, 0);
        acc2 = __builtin_amdgcn_mfma_f32_16x16x32_bf16(a, b2, acc2, 0, 0, 0);
        acc3 = __builtin_amdgcn_mfma_f32_16x16x32_bf16(a, b3, acc3, 0, 0, 0);
    }

#pragma unroll
    for (int r = 0; r < 4; ++r) {
        int node = node0 + wv * 16 + quad * 4 + r;
        if (node < n) {
            size_t base = (size_t)node * OUT_C + l16;
            y[base + 0]  = f2bf(acc0[r]);
            y[base + 16] = f2bf(acc1[r]);
            y[base + 32] = f2bf(acc2[r]);
            y[base + 48] = f2bf(acc3[r]);
        }
    }
}

// ================= gather hop: 8 lanes per node (uint4), 8 nodes per wave =================
// Lane c (0..7) owns dwords 4c..4c+3 (channels 8c..8c+7) of its node's 128B row
// (uint4 loads, 8 lanes x 16B = 128B fully coalesced). 16 slots per iteration.
// csr loads are UNPREDICATED (csr has 16 zeroed tail entries at [E,E+16));
// validity is a weight mask: w = (slot<end) ? dec_w(p)*dinv_dst : 0. Slots
// beyond end hold other nodes' valid entries -> finite data, zero weight.
// Edge weight = dinv[src] (stored bf15) * dinv[dst] (f32, loaded once/node).
// Per-channel accumulation order: self -> bank0, slot k -> bank k&3, then
// (e0+e1)+(e2+e3) — same as previous layouts.

template <bool FINAL>
__global__ void gather_kernel(const unsigned short* __restrict__ src,
                              unsigned short* __restrict__ dst_bf,
                              float* __restrict__ dst_f32,
                              const int* __restrict__ row_start, const unsigned* __restrict__ csr,
                              const float* __restrict__ dinv, const float* __restrict__ bias,
                              int n) {
    int node = blockIdx.x * (blockDim.x >> 3) + (threadIdx.x >> 3);
    if (node >= n) return;
    int c = threadIdx.x & 7;                 // uint4 index within the row
    const uint4* srcp = (const uint4*)src;

    int beg = row_start[node];
    int end = row_start[node + 1];

    float s = dinv[node];
    float ss = s * s;

    // self-loop -> bank 0
    uint4 pv = srcp[(size_t)node * 8 + c];
    float e0[8], e1[8], e2[8], e3[8];
    e0[0] = ss * lo_bf(pv.x); e0[1] = ss * hi_bf(pv.x);
    e0[2] = ss * lo_bf(pv.y); e0[3] = ss * hi_bf(pv.y);
    e0[4] = ss * lo_bf(pv.z); e0[5] = ss * hi_bf(pv.z);
    e0[6] = ss * lo_bf(pv.w); e0[7] = ss * hi_bf(pv.w);
#pragma unroll
    for (int k = 0; k < 8; ++k) { e1[k] = 0.f; e2[k] = 0.f; e3[k] = 0.f; }

    for (int j0 = beg; j0 < end; j0 += 16) {
        unsigned p0 = csr[j0];
        unsigned p1 = csr[j0 + 1];
        unsigned p2 = csr[j0 + 2];
        unsigned p3 = csr[j0 + 3];
        unsigned p4 = csr[j0 + 4];
        unsigned p5 = csr[j0 + 5];
        unsigned p6 = csr[j0 + 6];
        unsigned p7 = csr[j0 + 7];
        unsigned p8 = csr[j0 + 8];
        unsigned p9 = csr[j0 + 9];
        unsigned pa = csr[j0 + 10];
        unsigned pb = csr[j0 + 11];
        unsigned pc = csr[j0 + 12];
        unsigned pd = csr[j0 + 13];
        unsigned pe = csr[j0 + 14];
        unsigned pf = csr[j0 + 15];
        uint4 v0 = srcp[(size_t)(p0 >> 15) * 8 + c];
        uint4 v1 = srcp[(size_t)(p1 >> 15) * 8 + c];
        uint4 v2 = srcp[(size_t)(p2 >> 15) * 8 + c];
        uint4 v3 = srcp[(size_t)(p3 >> 15) * 8 + c];
        uint4 v4 = srcp[(size_t)(p4 >> 15) * 8 + c];
        uint4 v5 = srcp[(size_t)(p5 >> 15) * 8 + c];
        uint4 v6 = srcp[(size_t)(p6 >> 15) * 8 + c];
        uint4 v7 = srcp[(size_t)(p7 >> 15) * 8 + c];
        uint4 v8 = srcp[(size_t)(p8 >> 15) * 8 + c];
        uint4 v9 = srcp[(size_t)(p9 >> 15) * 8 + c];
        uint4 va = srcp[(size_t)(pa >> 15) * 8 + c];
        uint4 vb = srcp[(size_t)(pb >> 15) * 8 + c];
        uint4 vc = srcp[(size_t)(pc >> 15) * 8 + c];
        uint4 vd = srcp[(size_t)(pd >> 15) * 8 + c];
        uint4 ve = srcp[(size_t)(pe >> 15) * 8 + c];
        uint4 vf = srcp[(size_t)(pf >> 15) * 8 + c];
        float w0 = (j0 + 0  < end) ? dec_w(p0) * s : 0.f;
        float w1 = (j0 + 1  < end) ? dec_w(p1) * s : 0.f;
        float w2 = (j0 + 2  < end) ? dec_w(p2) * s : 0.f;
        float w3 = (j0 + 3  < end) ? dec_w(p3) * s : 0.f;
        float w4 = (j0 + 4  < end) ? dec_w(p4) * s : 0.f;
        float w5 = (j0 + 5  < end) ? dec_w(p5) * s : 0.f;
        float w6 = (j0 + 6  < end) ? dec_w(p6) * s : 0.f;
        float w7 = (j0 + 7  < end) ? dec_w(p7) * s : 0.f;
        float w8 = (j0 + 8  < end) ? dec_w(p8) * s : 0.f;
        float w9 = (j0 + 9  < end) ? dec_w(p9) * s : 0.f;
        float wa = (j0 + 10 < end) ? dec_w(pa) * s : 0.f;
        float wb = (j0 + 11 < end) ? dec_w(pb) * s : 0.f;
        float wc = (j0 + 12 < end) ? dec_w(pc) * s : 0.f;
        float wd = (j0 + 13 < end) ? dec_w(pd) * s : 0.f;
        float we = (j0 + 14 < end) ? dec_w(pe) * s : 0.f;
        float wf = (j0 + 15 < end) ? dec_w(pf) * s : 0.f;
        e0[0] += w0 * lo_bf(v0.x); e0[1] += w0 * hi_bf(v0.x); e0[2] += w0 * lo_bf(v0.y); e0[3] += w0 * hi_bf(v0.y);
        e0[4] += w0 * lo_bf(v0.z); e0[5] += w0 * hi_bf(v0.z); e0[6] += w0 * lo_bf(v0.w); e0[7] += w0 * hi_bf(v0.w);
        e1[0] += w1 * lo_bf(v1.x); e1[1] += w1 * hi_bf(v1.x); e1[2] += w1 * lo_bf(v1.y); e1[3] += w1 * hi_bf(v1.y);
        e1[4] += w1 * lo_bf(v1.z); e1[5] += w1 * hi_bf(v1.z); e1[6] += w1 * lo_bf(v1.w); e1[7] += w1 * hi_bf(v1.w);
        e2[0] += w2 * lo_bf(v2.x); e2[1] += w2 * hi_bf(v2.x); e2[2] += w2 * lo_bf(v2.y); e2[3] += w2 * hi_bf(v2.y);
        e2[4] += w2 * lo_bf(v2.z); e2[5] += w2 * hi_bf(v2.z); e2[6] += w2 * lo_bf(v2.w); e2[7] += w2 * hi_bf(v2.w);
        e3[0] += w3 * lo_bf(v3.x); e3[1] += w3 * hi_bf(v3.x); e3[2] += w3 * lo_bf(v3.y); e3[3] += w3 * hi_bf(v3.y);
        e3[4] += w3 * lo_bf(v3.z); e3[5] += w3 * hi_bf(v3.z); e3[6] += w3 * lo_bf(v3.w); e3[7] += w3 * hi_bf(v3.w);
        e0[0] += w4 * lo_bf(v4.x); e0[1] += w4 * hi_bf(v4.x); e0[2] += w4 * lo_bf(v4.y); e0[3] += w4 * hi_bf(v4.y);
        e0[4] += w4 * lo_bf(v4.z); e0[5] += w4 * hi_bf(v4.z); e0[6] += w4 * lo_bf(v4.w); e0[7] += w4 * hi_bf(v4.w);
        e1[0] += w5 * lo_bf(v5.x); e1[1] += w5 * hi_bf(v5.x); e1[2] += w5 * lo_bf(v5.y); e1[3] += w5 * hi_bf(v5.y);
        e1[4] += w5 * lo_bf(v5.z); e1[5] += w5 * hi_bf(v5.z); e1[6] += w5 * lo_bf(v5.w); e1[7] += w5 * hi_bf(v5.w);
        e2[0] += w6 * lo_bf(v6.x); e2[1] += w6 * hi_bf(v6.x); e2[2] += w6 * lo_bf(v6.y); e2[3] += w6 * hi_bf(v6.y);
        e2[4] += w6 * lo_bf(v6.z); e2[5] += w6 * hi_bf(v6.z); e2[6] += w6 * lo_bf(v6.w); e2[7] += w6 * hi_bf(v6.w);
        e3[0] += w7 * lo_bf(v7.x); e3[1] += w7 * hi_bf(v7.x); e3[2] += w7 * lo_bf(v7.y); e3[3] += w7 * hi_bf(v7.y);
        e3[4] += w7 * lo_bf(v7.z); e3[5] += w7 * hi_bf(v7.z); e3[6] += w7 * lo_bf(v7.w); e3[7] += w7 * hi_bf(v7.w);
        e0[0] += w8 * lo_bf(v8.x); e0[1] += w8 * hi_bf(v8.x); e0[2] += w8 * lo_bf(v8.y); e0[3] += w8 * hi_bf(v8.y);
        e0[4] += w8 * lo_bf(v8.z); e0[5] += w8 * hi_bf(v8.z); e0[6] += w8 * lo_bf(v8.w); e0[7] += w8 * hi_bf(v8.w);
        e1[0] += w9 * lo_bf(v9.x); e1[1] += w9 * hi_bf(v9.x); e1[2] += w9 * lo_bf(v9.y); e1[3] += w9 * hi_bf(v9.y);
        e1[4] += w9 * lo_bf(v9.z); e1[5] += w9 * hi_bf(v9.z); e1[6] += w9 * lo_bf(v9.w); e1[7] += w9 * hi_bf(v9.w);
        e2[0] += wa * lo_bf(va.x); e2[1] += wa * hi_bf(va.x); e2[2] += wa * lo_bf(va.y); e2[3] += wa * hi_bf(va.y);
        e2[4] += wa * lo_bf(va.z); e2[5] += wa * hi_bf(va.z); e2[6] += wa * lo_bf(va.w); e2[7] += wa * hi_bf(va.w);
        e3[0] += wb * lo_bf(vb.x); e3[1] += wb * hi_bf(vb.x); e3[2] += wb * lo_bf(vb.y); e3[3] += wb * hi_bf(vb.y);
        e3[4] += wb * lo_bf(vb.z); e3[5] += wb * hi_bf(vb.z); e3[6] += wb * lo_bf(vb.w); e3[7] += wb * hi_bf(vb.w);
        e0[0] += wc * lo_bf(vc.x); e0[1] += wc * hi_bf(vc.x); e0[2] += wc * lo_bf(vc.y); e0[3] += wc * hi_bf(vc.y);
        e0[4] += wc * lo_bf(vc.z); e0[5] += wc * hi_bf(vc.z); e0[6] += wc * lo_bf(vc.w); e0[7] += wc * hi_bf(vc.w);
        e1[0] += wd * lo_bf(vd.x); e1[1] += wd * hi_bf(vd.x); e1[2] += wd * lo_bf(vd.y); e1[3] += wd * hi_bf(vd.y);
        e1[4] += wd * lo_bf(vd.z); e1[5] += wd * hi_bf(vd.z); e1[6] += wd * lo_bf(vd.w); e1[7] += wd * hi_bf(vd.w);
        e2[0] += we * lo_bf(ve.x); e2[1] += we * hi_bf(ve.x); e2[2] += we * lo_bf(ve.y); e2[3] += we * hi_bf(ve.y);
        e2[4] += we * lo_bf(ve.z); e2[5] += we * hi_bf(ve.z); e2[6] += we * lo_bf(ve.w); e2[7] += we * hi_bf(ve.w);
        e3[0] += wf * lo_bf(vf.x); e3[1] += wf * hi_bf(vf.x); e3[2] += wf * lo_bf(vf.y); e3[3] += wf * hi_bf(vf.y);
        e3[4] += wf * lo_bf(vf.z); e3[5] += wf * hi_bf(vf.z); e3[6] += wf * lo_bf(vf.w); e3[7] += wf * hi_bf(vf.w);
    }

    float a[8];
#pragma unroll
    for (int k = 0; k < 8; ++k) a[k] = (e0[k] + e1[k]) + (e2[k] + e3[k]);

    if (FINAL) {
        const float4* bp = (const float4*)bias;
        float4 b0 = bp[c * 2];
        float4 b1 = bp[c * 2 + 1];
        float4 o0, o1;
        o0.x = 1.0f / (1.0f + __expf(-(a[0] + b0.x)));
        o0.y = 1.0f / (1.0f + __expf(-(a[1] + b0.y)));
        o0.z = 1.0f / (1.0f + __expf(-(a[2] + b0.z)));
        o0.w = 1.0f / (1.0f + __expf(-(a[3] + b0.w)));
        o1.x = 1.0f / (1.0f + __expf(-(a[4] + b1.x)));
        o1.y = 1.0f / (1.0f + __expf(-(a[5] + b1.y)));
        o1.z = 1.0f / (1.0f + __expf(-(a[6] + b1.z)));
        o1.w = 1.0f / (1.0f + __expf(-(a[7] + b1.w)));
        ((float4*)dst_f32)[(size_t)node * 16 + c * 2] = o0;
        ((float4*)dst_f32)[(size_t)node * 16 + c * 2 + 1] = o1;
    } else {
        uint4 o;
        o.x = pack2bf(a[0], a[1]);
        o.y = pack2bf(a[2], a[3]);
        o.z = pack2bf(a[4], a[5]);
        o.w = pack2bf(a[6], a[7]);
        ((uint4*)dst_bf)[(size_t)node * 8 + c] = o;
    }
}

// ================= launch =================

static inline size_t align16(size_t x) { return (x + 15) & ~(size_t)15; }

extern "C" void kernel_launch(void* const* d_in, const int* in_sizes, int n_in,
                              void* d_out, int out_size, void* d_ws, size_t ws_size,
                              hipStream_t stream) {
    const float* x = (const float*)d_in[0];
    const int* edge_index = (const int*)d_in[1];
    const float* W = (const float*)d_in[2];
    const float* b = (const float*)d_in[3];
    float* out = (float*)d_out;

    const int N = N_NODES;
    const int E = in_sizes[1] / 2;

    const int* row = edge_index;        // source
    const int* col = edge_index + E;    // destination

    char* ws = (char*)d_ws;
    size_t off = 0;
    int* cnt = (int*)(ws + off);             off = align16(off + (size_t)N * 4);
    float* dinv = (float*)(ws + off);        off = align16(off + (size_t)N * 4);
    int* row_start = (int*)(ws + off);       off = align16(off + (size_t)(N + 1) * 4);
    int* partials = (int*)(ws + off);        off = align16(off + 512 * 4);
    unsigned* csr = (unsigned*)(ws + off);   off = align16(off + (size_t)(E + 16) * 4);
    unsigned short* y0 = (unsigned short*)(ws + off); off = align16(off + (size_t)N * OUT_C * 2);
    unsigned short* y1 = (unsigned short*)(ws + off); off = align16(off + (size_t)N * OUT_C * 2);
    // eidx lifetime (count -> fill) is disjoint from y1 (gather1 -> gather2): alias.
    unsigned short* eidx = y1;

    const int B = 256;
    const int nb_e = (E + B - 1) / B;               // 3125
    const int nb_scan = (N + SCAN_B - 1) / SCAN_B;  // 196
    const int nb_lin = (N + 63) / 64;               // 1563
    int nbg = nb_lin;                                // groups of {2 fill, 1 linear}
    if (2 * nbg < nb_e) nbg = (nb_e + 1) / 2;

    // ---- CSR metadata ----
    hipMemsetAsync(cnt, 0, (size_t)N * 4, stream);
    count_kernel<<<nb_e, B, 0, stream>>>(col, cnt, eidx, csr, E);
    scan_pass1_kernel<<<nb_scan, SCAN_B, 0, stream>>>(cnt, partials, N);
    scan23_kernel<<<nb_scan, SCAN_B, 0, stream>>>(cnt, partials, row_start, dinv, N, nb_scan);

    // ---- fused: csr_fill (atomic-free) + linear, interleaved 2:1 ----
    fill_linear_kernel<<<3 * nbg, B, 0, stream>>>(row, col, dinv, row_start, eidx, csr, E,
                                                  x, W, y0, N, nb_lin);

    // ---- hop 1 (32 nodes per 256-thread block) ----
    gather_kernel<false><<<(N + 31) / 32, B, 0, stream>>>(y0, y1, nullptr, row_start, csr, dinv, b, N);

    // ---- hop 2 + bias + sigmoid ----
    gather_kernel<true><<<(N + 31) / 32, B, 0, stream>>>(y1, nullptr, out, row_start, csr, dinv, b, N);
}

// Round 11
// 209.613 us; speedup vs baseline: 1.1223x; 1.1223x over previous
//
#include <hip/hip_runtime.h>
#include <hip/hip_bf16.h>
#include <math.h>

#define N_NODES 100000
#define N_EDGES 800000
#define IN_C 96
#define OUT_C 64
#define C4 (IN_C / 4)   // 24 float4 chunks per node
#define XPAD 104        // padded LDS row stride in bf16 elems
#define SCAN_B 512      // scan block width

typedef __attribute__((ext_vector_type(8))) short bf16x8;
typedef __attribute__((ext_vector_type(4))) float f32x4;

// bf16 helpers (manual, deterministic RNE)
__device__ __forceinline__ unsigned short f2bf(float f) {
    unsigned u = __float_as_uint(f);
    unsigned r = 0x7FFFu + ((u >> 16) & 1u);
    return (unsigned short)((u + r) >> 16);
}
__device__ __forceinline__ unsigned pack2bf(float a, float b) {
    return (unsigned)f2bf(a) | ((unsigned)f2bf(b) << 16);
}
// packed csr entry: [src:17][dinv_src_bf15:15]  (dinv in (0,1] so sign bit 0)
__device__ __forceinline__ float dec_w(unsigned p) {
    return __uint_as_float((p & 0x7FFFu) << 16);
}
__device__ __forceinline__ float lo_bf(unsigned v) { return __uint_as_float(v << 16); }
__device__ __forceinline__ float hi_bf(unsigned v) { return __uint_as_float(v & 0xFFFF0000u); }

// ================= CSR build =================

// count in-degree AND record each edge's within-node slot (the atomic's return
// value) so the fill pass needs no second atomic. Also zeroes the 16 csr tail
// entries [e, e+16) so gather can load csr unpredicated.
__global__ void count_kernel(const int* __restrict__ col, int* __restrict__ cnt,
                             unsigned short* __restrict__ eidx,
                             unsigned* __restrict__ csr, int e) {
    int i = blockIdx.x * blockDim.x + threadIdx.x;
    if (i < 16) csr[e + i] = 0u;
    if (i < e) {
        int idx = atomicAdd(&cnt[col[i]], 1);
        eidx[i] = (unsigned short)idx;
    }
}

// per-512-block sums
__global__ void scan_pass1_kernel(const int* __restrict__ cnt, int* __restrict__ partials, int n) {
    __shared__ int s[SCAN_B];
    int i = blockIdx.x * SCAN_B + threadIdx.x;
    int v = (i < n) ? cnt[i] : 0;
    s[threadIdx.x] = v;
    __syncthreads();
    for (int off = SCAN_B / 2; off > 0; off >>= 1) {
        if (threadIdx.x < off) s[threadIdx.x] += s[threadIdx.x + off];
        __syncthreads();
    }
    if (threadIdx.x == 0) partials[blockIdx.x] = s[0];
}

// fused scan2+scan3: every block redundantly scans the partials (nparts<=512),
// then scans its own 512 cnt elements; writes row_start/dinv (+total).
__global__ void scan23_kernel(const int* __restrict__ cnt, const int* __restrict__ partials,
                              int* __restrict__ row_start, float* __restrict__ dinv,
                              int n, int nparts) {
    __shared__ int ps[SCAN_B];
    __shared__ int es[SCAN_B];
    int t = threadIdx.x;

    int pv = (t < nparts) ? partials[t] : 0;
    ps[t] = pv;
    __syncthreads();
    int run = pv;
    for (int off = 1; off < SCAN_B; off <<= 1) {
        int tmp = (t >= off) ? ps[t - off] : 0;
        __syncthreads();
        run += tmp;
        ps[t] = run;
        __syncthreads();
    }
    int total = ps[nparts - 1];
    __syncthreads();
    ps[t] = run - pv;   // exclusive
    __syncthreads();
    int block_off = ps[blockIdx.x];

    int i = blockIdx.x * SCAN_B + t;
    int v = (i < n) ? cnt[i] : 0;
    es[t] = v;
    __syncthreads();
    int erun = v;
    for (int off = 1; off < SCAN_B; off <<= 1) {
        int tmp = (t >= off) ? es[t - off] : 0;
        __syncthreads();
        erun += tmp;
        es[t] = erun;
        __syncthreads();
    }
    if (i < n) {
        int start = block_off + erun - v;   // exclusive
        row_start[i] = start;
        dinv[i] = rsqrtf((float)v + 1.0f);
    }
    if (blockIdx.x == 0 && t == 0) row_start[n] = total;
}

// ================= fused: csr_fill + linear, interleaved 2:1 =================
// blockIdx%3 in {0,1} -> fill block (atomic-free: pos = row_start[c]+eidx[i]).
//   Entry stores dinv[src] only (gather multiplies by dinv[dst]) -> one fewer
//   random load per edge than storing the product.
// blockIdx%3 == 2     -> linear block (MFMA x@W^T, W staged in LDS, x loaded
//                        global->reg directly: only 13.3KB LDS -> 8 blocks/CU).

__global__ void fill_linear_kernel(const int* __restrict__ row, const int* __restrict__ col,
                                   const float* __restrict__ dinv,
                                   const int* __restrict__ row_start,
                                   const unsigned short* __restrict__ eidx,
                                   unsigned* __restrict__ csr, int e,
                                   const float* __restrict__ x, const float* __restrict__ W,
                                   unsigned short* __restrict__ y, int n, int nb_lin) {
    __shared__ unsigned short wbf[64 * XPAD];

    int g = blockIdx.x / 3;
    int r3 = blockIdx.x - g * 3;
    if (r3 != 2) {
        int i = (g * 2 + r3) * 256 + threadIdx.x;
        if (i < e) {
            int r = row[i];
            int c = col[i];
            int pos = row_start[c] + (int)eidx[i];
            csr[pos] = ((unsigned)r << 15) | (unsigned)f2bf(dinv[r]);
        }
        return;
    }
    if (g >= nb_lin) return;

    int tid = threadIdx.x;
    int lane = tid & 63;
    int wv = tid >> 6;
    int node0 = g * 64;

    // stage W only (13.3KB)
    for (int i = tid; i < 64 * C4; i += 256) {
        int o = i / C4;
        int c4 = i - o * C4;
        float4 v = ((const float4*)(W + (size_t)o * IN_C))[c4];
        uint2 pk;
        pk.x = pack2bf(v.x, v.y);
        pk.y = pack2bf(v.z, v.w);
        *(uint2*)&wbf[o * XPAD + c4 * 4] = pk;
    }
    __syncthreads();

    int l16 = lane & 15;
    int quad = lane >> 4;

    // A-row for this lane: loaded straight from global (f32 -> bf16, same RNE)
    int arow = node0 + wv * 16 + l16;
    const float* xr = x + (size_t)((arow < n) ? arow : 0) * IN_C + quad * 8;

    f32x4 acc0 = {0.f, 0.f, 0.f, 0.f};
    f32x4 acc1 = {0.f, 0.f, 0.f, 0.f};
    f32x4 acc2 = {0.f, 0.f, 0.f, 0.f};
    f32x4 acc3 = {0.f, 0.f, 0.f, 0.f};

#pragma unroll
    for (int kc = 0; kc < 3; ++kc) {
        float4 v0 = ((const float4*)(xr + kc * 32))[0];
        float4 v1 = ((const float4*)(xr + kc * 32))[1];
        union { bf16x8 v; unsigned u[4]; } au;
        au.u[0] = pack2bf(v0.x, v0.y);
        au.u[1] = pack2bf(v0.z, v0.w);
        au.u[2] = pack2bf(v1.x, v1.y);
        au.u[3] = pack2bf(v1.z, v1.w);
        bf16x8 a = au.v;
        bf16x8 b0 = *(const bf16x8*)&wbf[(0 * 16 + l16) * XPAD + kc * 32 + quad * 8];
        bf16x8 b1 = *(const bf16x8*)&wbf[(1 * 16 + l16) * XPAD + kc * 32 + quad * 8];
        bf16x8 b2 = *(const bf16x8*)&wbf[(2 * 16 + l16) * XPAD + kc * 32 + quad * 8];
        bf16x8 b3 = *(const bf16x8*)&wbf[(3 * 16 + l16) * XPAD + kc * 32 + quad * 8];
        acc0 = __builtin_amdgcn_mfma_f32_16x16x32_bf16(a, b0, acc0, 0, 0, 0);
        acc1 = __builtin_amdgcn_mfma_f32_16x16x32_bf16(a, b1, acc1, 0, 0, 0);
        acc2 = __builtin_amdgcn_mfma_f32_16x16x32_bf16(a, b2, acc2, 0, 0, 0);
        acc3 = __builtin_amdgcn_mfma_f32_16x16x32_bf16(a, b3, acc3, 0, 0, 0);
    }

#pragma unroll
    for (int r = 0; r < 4; ++r) {
        int node = node0 + wv * 16 + quad * 4 + r;
        if (node < n) {
            size_t base = (size_t)node * OUT_C + l16;
            y[base + 0]  = f2bf(acc0[r]);
            y[base + 16] = f2bf(acc1[r]);
            y[base + 32] = f2bf(acc2[r]);
            y[base + 48] = f2bf(acc3[r]);
        }
    }
}

// ================= gather hop: 16 lanes per node (uint2), 4 nodes per wave =================
// R9's proven shape (uint2 loads: 16 lanes x 8B = 128B coalesced row; modest
// register footprint — R10's uint4x16 serialized on VGPR pressure).
// csr loads are UNPREDICATED (16 zeroed tail entries at [E,E+16)), then the
// ENTRY is masked: slot>=end -> p=0 -> w=+0.0 AND src=node 0 (hot line).
// R10's mistake was masking only the weight: tail slots fetched other nodes'
// random rows (+22MB FETCH at a ~3 TB/s traffic-bound ceiling).
// Edge weight = dinv[src] (stored bf15) * dinv[dst] (f32, loaded once/node).
// Per-channel accumulation order: self -> bank0, slot k -> bank k&3, then
// (e0+e1)+(e2+e3).

template <bool FINAL>
__global__ void gather_kernel(const unsigned short* __restrict__ src,
                              unsigned short* __restrict__ dst_bf,
                              float* __restrict__ dst_f32,
                              const int* __restrict__ row_start, const unsigned* __restrict__ csr,
                              const float* __restrict__ dinv, const float* __restrict__ bias,
                              int n) {
    int node = blockIdx.x * (blockDim.x >> 4) + (threadIdx.x >> 4);
    if (node >= n) return;
    int c = threadIdx.x & 15;                // dwords 2c, 2c+1
    const uint2* srcp = (const uint2*)src;

    int beg = row_start[node];
    int end = row_start[node + 1];

    // self-loop
    uint2 pv = srcp[(size_t)node * 16 + c];
    float s = dinv[node];
    float ss = s * s;

    float e0a = ss * lo_bf(pv.x), e0b = ss * hi_bf(pv.x);
    float e0c = ss * lo_bf(pv.y), e0d = ss * hi_bf(pv.y);
    float e1a = 0.f, e1b = 0.f, e1c = 0.f, e1d = 0.f;
    float e2a = 0.f, e2b = 0.f, e2c = 0.f, e2d = 0.f;
    float e3a = 0.f, e3b = 0.f, e3c = 0.f, e3d = 0.f;

    for (int j0 = beg; j0 < end; j0 += 16) {
        // unpredicated csr loads (tail entries [E,E+16) are zero)
        unsigned t0 = csr[j0];
        unsigned t1 = csr[j0 + 1];
        unsigned t2 = csr[j0 + 2];
        unsigned t3 = csr[j0 + 3];
        unsigned t4 = csr[j0 + 4];
        unsigned t5 = csr[j0 + 5];
        unsigned t6 = csr[j0 + 6];
        unsigned t7 = csr[j0 + 7];
        unsigned t8 = csr[j0 + 8];
        unsigned t9 = csr[j0 + 9];
        unsigned ta = csr[j0 + 10];
        unsigned tb = csr[j0 + 11];
        unsigned tc = csr[j0 + 12];
        unsigned td = csr[j0 + 13];
        unsigned te = csr[j0 + 14];
        unsigned tf = csr[j0 + 15];
        // mask the ENTRY: invalid slot -> w=0 AND src=node 0 (hot line)
        unsigned p0 = (j0 + 0  < end) ? t0 : 0u;
        unsigned p1 = (j0 + 1  < end) ? t1 : 0u;
        unsigned p2 = (j0 + 2  < end) ? t2 : 0u;
        unsigned p3 = (j0 + 3  < end) ? t3 : 0u;
        unsigned p4 = (j0 + 4  < end) ? t4 : 0u;
        unsigned p5 = (j0 + 5  < end) ? t5 : 0u;
        unsigned p6 = (j0 + 6  < end) ? t6 : 0u;
        unsigned p7 = (j0 + 7  < end) ? t7 : 0u;
        unsigned p8 = (j0 + 8  < end) ? t8 : 0u;
        unsigned p9 = (j0 + 9  < end) ? t9 : 0u;
        unsigned pa = (j0 + 10 < end) ? ta : 0u;
        unsigned pb = (j0 + 11 < end) ? tb : 0u;
        unsigned pc = (j0 + 12 < end) ? tc : 0u;
        unsigned pd = (j0 + 13 < end) ? td : 0u;
        unsigned pe = (j0 + 14 < end) ? te : 0u;
        unsigned pf = (j0 + 15 < end) ? tf : 0u;
        uint2 v0 = srcp[(size_t)(p0 >> 15) * 16 + c];
        uint2 v1 = srcp[(size_t)(p1 >> 15) * 16 + c];
        uint2 v2 = srcp[(size_t)(p2 >> 15) * 16 + c];
        uint2 v3 = srcp[(size_t)(p3 >> 15) * 16 + c];
        uint2 v4 = srcp[(size_t)(p4 >> 15) * 16 + c];
        uint2 v5 = srcp[(size_t)(p5 >> 15) * 16 + c];
        uint2 v6 = srcp[(size_t)(p6 >> 15) * 16 + c];
        uint2 v7 = srcp[(size_t)(p7 >> 15) * 16 + c];
        uint2 v8 = srcp[(size_t)(p8 >> 15) * 16 + c];
        uint2 v9 = srcp[(size_t)(p9 >> 15) * 16 + c];
        uint2 va = srcp[(size_t)(pa >> 15) * 16 + c];
        uint2 vb = srcp[(size_t)(pb >> 15) * 16 + c];
        uint2 vc = srcp[(size_t)(pc >> 15) * 16 + c];
        uint2 vd = srcp[(size_t)(pd >> 15) * 16 + c];
        uint2 ve = srcp[(size_t)(pe >> 15) * 16 + c];
        uint2 vf = srcp[(size_t)(pf >> 15) * 16 + c];
        float w0 = dec_w(p0) * s, w1 = dec_w(p1) * s, w2 = dec_w(p2) * s, w3 = dec_w(p3) * s;
        float w4 = dec_w(p4) * s, w5 = dec_w(p5) * s, w6 = dec_w(p6) * s, w7 = dec_w(p7) * s;
        float w8 = dec_w(p8) * s, w9 = dec_w(p9) * s, wa = dec_w(pa) * s, wb = dec_w(pb) * s;
        float wc = dec_w(pc) * s, wd = dec_w(pd) * s, we = dec_w(pe) * s, wf = dec_w(pf) * s;
        e0a += w0 * lo_bf(v0.x); e0b += w0 * hi_bf(v0.x); e0c += w0 * lo_bf(v0.y); e0d += w0 * hi_bf(v0.y);
        e1a += w1 * lo_bf(v1.x); e1b += w1 * hi_bf(v1.x); e1c += w1 * lo_bf(v1.y); e1d += w1 * hi_bf(v1.y);
        e2a += w2 * lo_bf(v2.x); e2b += w2 * hi_bf(v2.x); e2c += w2 * lo_bf(v2.y); e2d += w2 * hi_bf(v2.y);
        e3a += w3 * lo_bf(v3.x); e3b += w3 * hi_bf(v3.x); e3c += w3 * lo_bf(v3.y); e3d += w3 * hi_bf(v3.y);
        e0a += w4 * lo_bf(v4.x); e0b += w4 * hi_bf(v4.x); e0c += w4 * lo_bf(v4.y); e0d += w4 * hi_bf(v4.y);
        e1a += w5 * lo_bf(v5.x); e1b += w5 * hi_bf(v5.x); e1c += w5 * lo_bf(v5.y); e1d += w5 * hi_bf(v5.y);
        e2a += w6 * lo_bf(v6.x); e2b += w6 * hi_bf(v6.x); e2c += w6 * lo_bf(v6.y); e2d += w6 * hi_bf(v6.y);
        e3a += w7 * lo_bf(v7.x); e3b += w7 * hi_bf(v7.x); e3c += w7 * lo_bf(v7.y); e3d += w7 * hi_bf(v7.y);
        e0a += w8 * lo_bf(v8.x); e0b += w8 * hi_bf(v8.x); e0c += w8 * lo_bf(v8.y); e0d += w8 * hi_bf(v8.y);
        e1a += w9 * lo_bf(v9.x); e1b += w9 * hi_bf(v9.x); e1c += w9 * lo_bf(v9.y); e1d += w9 * hi_bf(v9.y);
        e2a += wa * lo_bf(va.x); e2b += wa * hi_bf(va.x); e2c += wa * lo_bf(va.y); e2d += wa * hi_bf(va.y);
        e3a += wb * lo_bf(vb.x); e3b += wb * hi_bf(vb.x); e3c += wb * lo_bf(vb.y); e3d += wb * hi_bf(vb.y);
        e0a += wc * lo_bf(vc.x); e0b += wc * hi_bf(vc.x); e0c += wc * lo_bf(vc.y); e0d += wc * hi_bf(vc.y);
        e1a += wd * lo_bf(vd.x); e1b += wd * hi_bf(vd.x); e1c += wd * lo_bf(vd.y); e1d += wd * hi_bf(vd.y);
        e2a += we * lo_bf(ve.x); e2b += we * hi_bf(ve.x); e2c += we * lo_bf(ve.y); e2d += we * hi_bf(ve.y);
        e3a += wf * lo_bf(vf.x); e3b += wf * hi_bf(vf.x); e3c += wf * lo_bf(vf.y); e3d += wf * hi_bf(vf.y);
    }
    float a0 = (e0a + e1a) + (e2a + e3a);
    float a1 = (e0b + e1b) + (e2b + e3b);
    float a2 = (e0c + e1c) + (e2c + e3c);
    float a3 = (e0d + e1d) + (e2d + e3d);

    if (FINAL) {
        float4 bb = ((const float4*)bias)[c];
        float4 o;
        o.x = 1.0f / (1.0f + __expf(-(a0 + bb.x)));
        o.y = 1.0f / (1.0f + __expf(-(a1 + bb.y)));
        o.z = 1.0f / (1.0f + __expf(-(a2 + bb.z)));
        o.w = 1.0f / (1.0f + __expf(-(a3 + bb.w)));
        ((float4*)dst_f32)[(size_t)node * 16 + c] = o;
    } else {
        uint2 o;
        o.x = pack2bf(a0, a1);
        o.y = pack2bf(a2, a3);
        ((uint2*)dst_bf)[(size_t)node * 16 + c] = o;
    }
}

// ================= launch =================

static inline size_t align16(size_t x) { return (x + 15) & ~(size_t)15; }

extern "C" void kernel_launch(void* const* d_in, const int* in_sizes, int n_in,
                              void* d_out, int out_size, void* d_ws, size_t ws_size,
                              hipStream_t stream) {
    const float* x = (const float*)d_in[0];
    const int* edge_index = (const int*)d_in[1];
    const float* W = (const float*)d_in[2];
    const float* b = (const float*)d_in[3];
    float* out = (float*)d_out;

    const int N = N_NODES;
    const int E = in_sizes[1] / 2;

    const int* row = edge_index;        // source
    const int* col = edge_index + E;    // destination

    char* ws = (char*)d_ws;
    size_t off = 0;
    int* cnt = (int*)(ws + off);             off = align16(off + (size_t)N * 4);
    float* dinv = (float*)(ws + off);        off = align16(off + (size_t)N * 4);
    int* row_start = (int*)(ws + off);       off = align16(off + (size_t)(N + 1) * 4);
    int* partials = (int*)(ws + off);        off = align16(off + 512 * 4);
    unsigned* csr = (unsigned*)(ws + off);   off = align16(off + (size_t)(E + 16) * 4);
    unsigned short* y0 = (unsigned short*)(ws + off); off = align16(off + (size_t)N * OUT_C * 2);
    unsigned short* y1 = (unsigned short*)(ws + off); off = align16(off + (size_t)N * OUT_C * 2);
    // eidx lifetime (count -> fill) is disjoint from y1 (gather1 -> gather2): alias.
    unsigned short* eidx = y1;

    const int B = 256;
    const int nb_e = (E + B - 1) / B;               // 3125
    const int nb_scan = (N + SCAN_B - 1) / SCAN_B;  // 196
    const int nb_lin = (N + 63) / 64;               // 1563
    int nbg = nb_lin;                                // groups of {2 fill, 1 linear}
    if (2 * nbg < nb_e) nbg = (nb_e + 1) / 2;

    // ---- CSR metadata ----
    hipMemsetAsync(cnt, 0, (size_t)N * 4, stream);
    count_kernel<<<nb_e, B, 0, stream>>>(col, cnt, eidx, csr, E);
    scan_pass1_kernel<<<nb_scan, SCAN_B, 0, stream>>>(cnt, partials, N);
    scan23_kernel<<<nb_scan, SCAN_B, 0, stream>>>(cnt, partials, row_start, dinv, N, nb_scan);

    // ---- fused: csr_fill (atomic-free) + linear, interleaved 2:1 ----
    fill_linear_kernel<<<3 * nbg, B, 0, stream>>>(row, col, dinv, row_start, eidx, csr, E,
                                                  x, W, y0, N, nb_lin);

    // ---- hop 1 (16 nodes per 256-thread block) ----
    gather_kernel<false><<<(N + 15) / 16, B, 0, stream>>>(y0, y1, nullptr, row_start, csr, dinv, b, N);

    // ---- hop 2 + bias + sigmoid ----
    gather_kernel<true><<<(N + 15) / 16, B, 0, stream>>>(y1, nullptr, out, row_start, csr, dinv, b, N);
}

// Round 14
// 189.129 us; speedup vs baseline: 1.2439x; 1.1083x over previous
//
#include <hip/hip_runtime.h>
#include <hip/hip_bf16.h>
#include <math.h>

#define N_NODES 100000
#define N_EDGES 800000
#define IN_C 96
#define OUT_C 64
#define C4 (IN_C / 4)   // 24 float4 chunks per node
#define XPAD 104        // padded LDS row stride in bf16 elems
#define SCAN_B 512      // scan block width

typedef __attribute__((ext_vector_type(8))) short bf16x8;
typedef __attribute__((ext_vector_type(4))) float f32x4;

// bf16 helpers (manual, deterministic RNE)
__device__ __forceinline__ unsigned short f2bf(float f) {
    unsigned u = __float_as_uint(f);
    unsigned r = 0x7FFFu + ((u >> 16) & 1u);
    return (unsigned short)((u + r) >> 16);
}
__device__ __forceinline__ unsigned pack2bf(float a, float b) {
    return (unsigned)f2bf(a) | ((unsigned)f2bf(b) << 16);
}
// packed csr entry: [src:17][dinv_src_bf15:15]
__device__ __forceinline__ float dec_w(unsigned p) {
    return __uint_as_float((p & 0x7FFFu) << 16);
}
// fp8 e4m3 (OCP on gfx950) via HW converts — encode and decode use the same
// instruction pair, so the format is self-consistent.
__device__ __forceinline__ unsigned char f2fp8(float f) {
    return (unsigned char)(__builtin_amdgcn_cvt_pk_fp8_f32(f, f, 0, false) & 0xFF);
}

// ================= CSR build =================

// count in-degree AND record each edge's within-node slot (the atomic's return
// value) so the fill pass needs no second atomic. Also zeroes the 16 csr tail
// entries [e, e+16) so gather can load csr unpredicated.
__global__ void count_kernel(const int* __restrict__ col, int* __restrict__ cnt,
                             unsigned short* __restrict__ eidx,
                             unsigned* __restrict__ csr, int e) {
    int i = blockIdx.x * blockDim.x + threadIdx.x;
    if (i < 16) csr[e + i] = 0u;
    if (i < e) {
        int idx = atomicAdd(&cnt[col[i]], 1);
        eidx[i] = (unsigned short)idx;
    }
}

// per-512-block sums
__global__ void scan_pass1_kernel(const int* __restrict__ cnt, int* __restrict__ partials, int n) {
    __shared__ int s[SCAN_B];
    int i = blockIdx.x * SCAN_B + threadIdx.x;
    int v = (i < n) ? cnt[i] : 0;
    s[threadIdx.x] = v;
    __syncthreads();
    for (int off = SCAN_B / 2; off > 0; off >>= 1) {
        if (threadIdx.x < off) s[threadIdx.x] += s[threadIdx.x + off];
        __syncthreads();
    }
    if (threadIdx.x == 0) partials[blockIdx.x] = s[0];
}

// fused scan2+scan3: every block redundantly scans the partials (nparts<=512),
// then scans its own 512 cnt elements; writes row_start/dinv (+total).
__global__ void scan23_kernel(const int* __restrict__ cnt, const int* __restrict__ partials,
                              int* __restrict__ row_start, float* __restrict__ dinv,
                              int n, int nparts) {
    __shared__ int ps[SCAN_B];
    __shared__ int es[SCAN_B];
    int t = threadIdx.x;

    int pv = (t < nparts) ? partials[t] : 0;
    ps[t] = pv;
    __syncthreads();
    int run = pv;
    for (int off = 1; off < SCAN_B; off <<= 1) {
        int tmp = (t >= off) ? ps[t - off] : 0;
        __syncthreads();
        run += tmp;
        ps[t] = run;
        __syncthreads();
    }
    int total = ps[nparts - 1];
    __syncthreads();
    ps[t] = run - pv;   // exclusive
    __syncthreads();
    int block_off = ps[blockIdx.x];

    int i = blockIdx.x * SCAN_B + t;
    int v = (i < n) ? cnt[i] : 0;
    es[t] = v;
    __syncthreads();
    int erun = v;
    for (int off = 1; off < SCAN_B; off <<= 1) {
        int tmp = (t >= off) ? es[t - off] : 0;
        __syncthreads();
        erun += tmp;
        es[t] = erun;
        __syncthreads();
    }
    if (i < n) {
        int start = block_off + erun - v;   // exclusive
        row_start[i] = start;
        dinv[i] = rsqrtf((float)v + 1.0f);
    }
    if (blockIdx.x == 0 && t == 0) row_start[n] = total;
}

// ================= fused: csr_fill + linear, interleaved 2:1 =================
// blockIdx%3 in {0,1} -> fill block (atomic-free: pos = row_start[c]+eidx[i]).
//   Entry stores dinv[src] only (gather multiplies by dinv[dst]).
// blockIdx%3 == 2     -> linear block (MFMA x@W^T, W staged in LDS, x loaded
//   global->reg). Epilogue stores y0 as fp8 e4m3 (64B rows: halves gather's
//   random-line traffic; lines pack 2 rows -> fewer unique line fills).

__global__ void fill_linear_kernel(const int* __restrict__ row, const int* __restrict__ col,
                                   const float* __restrict__ dinv,
                                   const int* __restrict__ row_start,
                                   const unsigned short* __restrict__ eidx,
                                   unsigned* __restrict__ csr, int e,
                                   const float* __restrict__ x, const float* __restrict__ W,
                                   unsigned char* __restrict__ y, int n, int nb_lin) {
    __shared__ unsigned short wbf[64 * XPAD];

    int g = blockIdx.x / 3;
    int r3 = blockIdx.x - g * 3;
    if (r3 != 2) {
        int i = (g * 2 + r3) * 256 + threadIdx.x;
        if (i < e) {
            int r = row[i];
            int c = col[i];
            int pos = row_start[c] + (int)eidx[i];
            csr[pos] = ((unsigned)r << 15) | (unsigned)f2bf(dinv[r]);
        }
        return;
    }
    if (g >= nb_lin) return;

    int tid = threadIdx.x;
    int lane = tid & 63;
    int wv = tid >> 6;
    int node0 = g * 64;

    // stage W only (13.3KB)
    for (int i = tid; i < 64 * C4; i += 256) {
        int o = i / C4;
        int c4 = i - o * C4;
        float4 v = ((const float4*)(W + (size_t)o * IN_C))[c4];
        uint2 pk;
        pk.x = pack2bf(v.x, v.y);
        pk.y = pack2bf(v.z, v.w);
        *(uint2*)&wbf[o * XPAD + c4 * 4] = pk;
    }
    __syncthreads();

    int l16 = lane & 15;
    int quad = lane >> 4;

    // A-row for this lane: loaded straight from global (f32 -> bf16, same RNE)
    int arow = node0 + wv * 16 + l16;
    const float* xr = x + (size_t)((arow < n) ? arow : 0) * IN_C + quad * 8;

    f32x4 acc0 = {0.f, 0.f, 0.f, 0.f};
    f32x4 acc1 = {0.f, 0.f, 0.f, 0.f};
    f32x4 acc2 = {0.f, 0.f, 0.f, 0.f};
    f32x4 acc3 = {0.f, 0.f, 0.f, 0.f};

#pragma unroll
    for (int kc = 0; kc < 3; ++kc) {
        float4 v0 = ((const float4*)(xr + kc * 32))[0];
        float4 v1 = ((const float4*)(xr + kc * 32))[1];
        union { bf16x8 v; unsigned u[4]; } au;
        au.u[0] = pack2bf(v0.x, v0.y);
        au.u[1] = pack2bf(v0.z, v0.w);
        au.u[2] = pack2bf(v1.x, v1.y);
        au.u[3] = pack2bf(v1.z, v1.w);
        bf16x8 a = au.v;
        bf16x8 b0 = *(const bf16x8*)&wbf[(0 * 16 + l16) * XPAD + kc * 32 + quad * 8];
        bf16x8 b1 = *(const bf16x8*)&wbf[(1 * 16 + l16) * XPAD + kc * 32 + quad * 8];
        bf16x8 b2 = *(const bf16x8*)&wbf[(2 * 16 + l16) * XPAD + kc * 32 + quad * 8];
        bf16x8 b3 = *(const bf16x8*)&wbf[(3 * 16 + l16) * XPAD + kc * 32 + quad * 8];
        acc0 = __builtin_amdgcn_mfma_f32_16x16x32_bf16(a, b0, acc0, 0, 0, 0);
        acc1 = __builtin_amdgcn_mfma_f32_16x16x32_bf16(a, b1, acc1, 0, 0, 0);
        acc2 = __builtin_amdgcn_mfma_f32_16x16x32_bf16(a, b2, acc2, 0, 0, 0);
        acc3 = __builtin_amdgcn_mfma_f32_16x16x32_bf16(a, b3, acc3, 0, 0, 0);
    }

#pragma unroll
    for (int r = 0; r < 4; ++r) {
        int node = node0 + wv * 16 + quad * 4 + r;
        if (node < n) {
            size_t base = (size_t)node * OUT_C + l16;
            y[base + 0]  = f2fp8(acc0[r]);
            y[base + 16] = f2fp8(acc1[r]);
            y[base + 32] = f2fp8(acc2[r]);
            y[base + 48] = f2fp8(acc3[r]);
        }
    }
}

// ================= gather hop: 16 lanes per node, fp8 rows, 4 nodes per wave =================
// Row = 64 fp8 ch = 64B; lane c (0..15) loads ONE dword = channels 4c..4c+3
// (16 lanes x 4B = 64B coalesced). Decode via HW v_cvt_f32_fp8 (1 op/ch, same
// cost as the old bf16 shifts). csr loads unpredicated (zeroed tail), ENTRY
// masked: invalid slot -> p=0 -> w=+0.0 AND src=node 0 (hot line).
// Accumulation bank order unchanged (self->bank0, slot k->bank k&3).

#define GACC(EA, EB, EC, ED, w, v) \
    EA += (w) * __builtin_amdgcn_cvt_f32_fp8((int)(v), 0); \
    EB += (w) * __builtin_amdgcn_cvt_f32_fp8((int)(v), 1); \
    EC += (w) * __builtin_amdgcn_cvt_f32_fp8((int)(v), 2); \
    ED += (w) * __builtin_amdgcn_cvt_f32_fp8((int)(v), 3);

template <bool FINAL>
__global__ void gather_kernel(const unsigned char* __restrict__ src,
                              unsigned char* __restrict__ dst_fp8,
                              float* __restrict__ dst_f32,
                              const int* __restrict__ row_start, const unsigned* __restrict__ csr,
                              const float* __restrict__ dinv, const float* __restrict__ bias,
                              int n) {
    int node = blockIdx.x * (blockDim.x >> 4) + (threadIdx.x >> 4);
    if (node >= n) return;
    int c = threadIdx.x & 15;                // dword index: channels 4c..4c+3
    const unsigned* srcp = (const unsigned*)src;

    int beg = row_start[node];
    int end = row_start[node + 1];

    // self-loop
    unsigned pv = srcp[(size_t)node * 16 + c];
    float s = dinv[node];
    float ss = s * s;

    float e0a = 0.f, e0b = 0.f, e0c = 0.f, e0d = 0.f;
    float e1a = 0.f, e1b = 0.f, e1c = 0.f, e1d = 0.f;
    float e2a = 0.f, e2b = 0.f, e2c = 0.f, e2d = 0.f;
    float e3a = 0.f, e3b = 0.f, e3c = 0.f, e3d = 0.f;
    GACC(e0a, e0b, e0c, e0d, ss, pv)

    for (int j0 = beg; j0 < end; j0 += 16) {
        unsigned t0 = csr[j0];
        unsigned t1 = csr[j0 + 1];
        unsigned t2 = csr[j0 + 2];
        unsigned t3 = csr[j0 + 3];
        unsigned t4 = csr[j0 + 4];
        unsigned t5 = csr[j0 + 5];
        unsigned t6 = csr[j0 + 6];
        unsigned t7 = csr[j0 + 7];
        unsigned t8 = csr[j0 + 8];
        unsigned t9 = csr[j0 + 9];
        unsigned ta = csr[j0 + 10];
        unsigned tb = csr[j0 + 11];
        unsigned tc = csr[j0 + 12];
        unsigned td = csr[j0 + 13];
        unsigned te = csr[j0 + 14];
        unsigned tf = csr[j0 + 15];
        unsigned p0 = (j0 + 0  < end) ? t0 : 0u;
        unsigned p1 = (j0 + 1  < end) ? t1 : 0u;
        unsigned p2 = (j0 + 2  < end) ? t2 : 0u;
        unsigned p3 = (j0 + 3  < end) ? t3 : 0u;
        unsigned p4 = (j0 + 4  < end) ? t4 : 0u;
        unsigned p5 = (j0 + 5  < end) ? t5 : 0u;
        unsigned p6 = (j0 + 6  < end) ? t6 : 0u;
        unsigned p7 = (j0 + 7  < end) ? t7 : 0u;
        unsigned p8 = (j0 + 8  < end) ? t8 : 0u;
        unsigned p9 = (j0 + 9  < end) ? t9 : 0u;
        unsigned pa = (j0 + 10 < end) ? ta : 0u;
        unsigned pb = (j0 + 11 < end) ? tb : 0u;
        unsigned pc = (j0 + 12 < end) ? tc : 0u;
        unsigned pd = (j0 + 13 < end) ? td : 0u;
        unsigned pe = (j0 + 14 < end) ? te : 0u;
        unsigned pf = (j0 + 15 < end) ? tf : 0u;
        unsigned v0 = srcp[(size_t)(p0 >> 15) * 16 + c];
        unsigned v1 = srcp[(size_t)(p1 >> 15) * 16 + c];
        unsigned v2 = srcp[(size_t)(p2 >> 15) * 16 + c];
        unsigned v3 = srcp[(size_t)(p3 >> 15) * 16 + c];
        unsigned v4 = srcp[(size_t)(p4 >> 15) * 16 + c];
        unsigned v5 = srcp[(size_t)(p5 >> 15) * 16 + c];
        unsigned v6 = srcp[(size_t)(p6 >> 15) * 16 + c];
        unsigned v7 = srcp[(size_t)(p7 >> 15) * 16 + c];
        unsigned v8 = srcp[(size_t)(p8 >> 15) * 16 + c];
        unsigned v9 = srcp[(size_t)(p9 >> 15) * 16 + c];
        unsigned va = srcp[(size_t)(pa >> 15) * 16 + c];
        unsigned vb = srcp[(size_t)(pb >> 15) * 16 + c];
        unsigned vc = srcp[(size_t)(pc >> 15) * 16 + c];
        unsigned vd = srcp[(size_t)(pd >> 15) * 16 + c];
        unsigned ve = srcp[(size_t)(pe >> 15) * 16 + c];
        unsigned vf = srcp[(size_t)(pf >> 15) * 16 + c];
        float w0 = dec_w(p0) * s, w1 = dec_w(p1) * s, w2 = dec_w(p2) * s, w3 = dec_w(p3) * s;
        float w4 = dec_w(p4) * s, w5 = dec_w(p5) * s, w6 = dec_w(p6) * s, w7 = dec_w(p7) * s;
        float w8 = dec_w(p8) * s, w9 = dec_w(p9) * s, wa = dec_w(pa) * s, wb = dec_w(pb) * s;
        float wc = dec_w(pc) * s, wd = dec_w(pd) * s, we = dec_w(pe) * s, wf = dec_w(pf) * s;
        GACC(e0a, e0b, e0c, e0d, w0, v0)
        GACC(e1a, e1b, e1c, e1d, w1, v1)
        GACC(e2a, e2b, e2c, e2d, w2, v2)
        GACC(e3a, e3b, e3c, e3d, w3, v3)
        GACC(e0a, e0b, e0c, e0d, w4, v4)
        GACC(e1a, e1b, e1c, e1d, w5, v5)
        GACC(e2a, e2b, e2c, e2d, w6, v6)
        GACC(e3a, e3b, e3c, e3d, w7, v7)
        GACC(e0a, e0b, e0c, e0d, w8, v8)
        GACC(e1a, e1b, e1c, e1d, w9, v9)
        GACC(e2a, e2b, e2c, e2d, wa, va)
        GACC(e3a, e3b, e3c, e3d, wb, vb)
        GACC(e0a, e0b, e0c, e0d, wc, vc)
        GACC(e1a, e1b, e1c, e1d, wd, vd)
        GACC(e2a, e2b, e2c, e2d, we, ve)
        GACC(e3a, e3b, e3c, e3d, wf, vf)
    }
    float a0 = (e0a + e1a) + (e2a + e3a);
    float a1 = (e0b + e1b) + (e2b + e3b);
    float a2 = (e0c + e1c) + (e2c + e3c);
    float a3 = (e0d + e1d) + (e2d + e3d);

    if (FINAL) {
        float4 bb = ((const float4*)bias)[c];
        float4 o;
        o.x = 1.0f / (1.0f + __expf(-(a0 + bb.x)));
        o.y = 1.0f / (1.0f + __expf(-(a1 + bb.y)));
        o.z = 1.0f / (1.0f + __expf(-(a2 + bb.z)));
        o.w = 1.0f / (1.0f + __expf(-(a3 + bb.w)));
        ((float4*)dst_f32)[(size_t)node * 16 + c] = o;
    } else {
        unsigned o = (unsigned)__builtin_amdgcn_cvt_pk_fp8_f32(a0, a1, 0, false);
        o = (unsigned)__builtin_amdgcn_cvt_pk_fp8_f32(a2, a3, (int)o, true);
        ((unsigned*)dst_fp8)[(size_t)node * 16 + c] = o;
    }
}

// ================= launch =================

static inline size_t align16(size_t x) { return (x + 15) & ~(size_t)15; }

extern "C" void kernel_launch(void* const* d_in, const int* in_sizes, int n_in,
                              void* d_out, int out_size, void* d_ws, size_t ws_size,
                              hipStream_t stream) {
    const float* x = (const float*)d_in[0];
    const int* edge_index = (const int*)d_in[1];
    const float* W = (const float*)d_in[2];
    const float* b = (const float*)d_in[3];
    float* out = (float*)d_out;

    const int N = N_NODES;
    const int E = in_sizes[1] / 2;

    const int* row = edge_index;        // source
    const int* col = edge_index + E;    // destination

    char* ws = (char*)d_ws;
    size_t off = 0;
    int* cnt = (int*)(ws + off);             off = align16(off + (size_t)N * 4);
    float* dinv = (float*)(ws + off);        off = align16(off + (size_t)N * 4);
    int* row_start = (int*)(ws + off);       off = align16(off + (size_t)(N + 1) * 4);
    int* partials = (int*)(ws + off);        off = align16(off + 512 * 4);
    unsigned* csr = (unsigned*)(ws + off);   off = align16(off + (size_t)(E + 16) * 4);
    unsigned char* y0 = (unsigned char*)(ws + off); off = align16(off + (size_t)N * OUT_C);
    unsigned char* y1 = (unsigned char*)(ws + off); off = align16(off + (size_t)N * OUT_C);
    // eidx lifetime (count -> fill) is disjoint from y1 (gather1 -> gather2): alias.
    unsigned short* eidx = (unsigned short*)y1;   // 1.6MB < 6.4MB

    const int B = 256;
    const int nb_e = (E + B - 1) / B;               // 3125
    const int nb_scan = (N + SCAN_B - 1) / SCAN_B;  // 196
    const int nb_lin = (N + 63) / 64;               // 1563
    int nbg = nb_lin;                                // groups of {2 fill, 1 linear}
    if (2 * nbg < nb_e) nbg = (nb_e + 1) / 2;

    // ---- CSR metadata ----
    hipMemsetAsync(cnt, 0, (size_t)N * 4, stream);
    count_kernel<<<nb_e, B, 0, stream>>>(col, cnt, eidx, csr, E);
    scan_pass1_kernel<<<nb_scan, SCAN_B, 0, stream>>>(cnt, partials, N);
    scan23_kernel<<<nb_scan, SCAN_B, 0, stream>>>(cnt, partials, row_start, dinv, N, nb_scan);

    // ---- fused: csr_fill (atomic-free) + linear, interleaved 2:1 ----
    fill_linear_kernel<<<3 * nbg, B, 0, stream>>>(row, col, dinv, row_start, eidx, csr, E,
                                                  x, W, y0, N, nb_lin);

    // ---- hop 1 (16 nodes per 256-thread block) ----
    gather_kernel<false><<<(N + 15) / 16, B, 0, stream>>>(y0, y1, nullptr, row_start, csr, dinv, b, N);

    // ---- hop 2 + bias + sigmoid ----
    gather_kernel<true><<<(N + 15) / 16, B, 0, stream>>>(y1, nullptr, out, row_start, csr, dinv, b, N);
}

// Round 15
// 183.655 us; speedup vs baseline: 1.2809x; 1.0298x over previous
//
#include <hip/hip_runtime.h>
#include <hip/hip_bf16.h>
#include <math.h>

#define N_NODES 100000
#define N_EDGES 800000
#define IN_C 96
#define OUT_C 64
#define C4 (IN_C / 4)   // 24 float4 chunks per node
#define XPAD 104        // padded LDS row stride in bf16 elems
#define SCAN_B 512      // scan block width

typedef __attribute__((ext_vector_type(8))) short bf16x8;
typedef __attribute__((ext_vector_type(4))) float f32x4;

// bf16 helpers (manual, deterministic RNE)
__device__ __forceinline__ unsigned short f2bf(float f) {
    unsigned u = __float_as_uint(f);
    unsigned r = 0x7FFFu + ((u >> 16) & 1u);
    return (unsigned short)((u + r) >> 16);
}
__device__ __forceinline__ unsigned pack2bf(float a, float b) {
    return (unsigned)f2bf(a) | ((unsigned)f2bf(b) << 16);
}
// packed csr entry: [src:17][dinv_src_bf15:15]
__device__ __forceinline__ float dec_w(unsigned p) {
    return __uint_as_float((p & 0x7FFFu) << 16);
}
// fp8 e4m3 (OCP on gfx950) via HW converts — encode and decode use the same
// instruction pair, so the format is self-consistent.
__device__ __forceinline__ unsigned char f2fp8(float f) {
    return (unsigned char)(__builtin_amdgcn_cvt_pk_fp8_f32(f, f, 0, false) & 0xFF);
}

// ================= shared linear block body (MFMA x@W^T for 64 nodes) =================
// Byte-identical math to R14's fill_linear epilogue (fp8 y rows).
__device__ __forceinline__ void linear_block(int g, int tid,
                                             const float* __restrict__ x,
                                             const float* __restrict__ W,
                                             unsigned char* __restrict__ y, int n,
                                             unsigned short* wbf) {
    int lane = tid & 63;
    int wv = tid >> 6;
    int node0 = g * 64;

    // stage W only (13.3KB)
    for (int i = tid; i < 64 * C4; i += 256) {
        int o = i / C4;
        int c4 = i - o * C4;
        float4 v = ((const float4*)(W + (size_t)o * IN_C))[c4];
        uint2 pk;
        pk.x = pack2bf(v.x, v.y);
        pk.y = pack2bf(v.z, v.w);
        *(uint2*)&wbf[o * XPAD + c4 * 4] = pk;
    }
    __syncthreads();

    int l16 = lane & 15;
    int quad = lane >> 4;

    // A-row for this lane: loaded straight from global (f32 -> bf16, same RNE)
    int arow = node0 + wv * 16 + l16;
    const float* xr = x + (size_t)((arow < n) ? arow : 0) * IN_C + quad * 8;

    f32x4 acc0 = {0.f, 0.f, 0.f, 0.f};
    f32x4 acc1 = {0.f, 0.f, 0.f, 0.f};
    f32x4 acc2 = {0.f, 0.f, 0.f, 0.f};
    f32x4 acc3 = {0.f, 0.f, 0.f, 0.f};

#pragma unroll
    for (int kc = 0; kc < 3; ++kc) {
        float4 v0 = ((const float4*)(xr + kc * 32))[0];
        float4 v1 = ((const float4*)(xr + kc * 32))[1];
        union { bf16x8 v; unsigned u[4]; } au;
        au.u[0] = pack2bf(v0.x, v0.y);
        au.u[1] = pack2bf(v0.z, v0.w);
        au.u[2] = pack2bf(v1.x, v1.y);
        au.u[3] = pack2bf(v1.z, v1.w);
        bf16x8 a = au.v;
        bf16x8 b0 = *(const bf16x8*)&wbf[(0 * 16 + l16) * XPAD + kc * 32 + quad * 8];
        bf16x8 b1 = *(const bf16x8*)&wbf[(1 * 16 + l16) * XPAD + kc * 32 + quad * 8];
        bf16x8 b2 = *(const bf16x8*)&wbf[(2 * 16 + l16) * XPAD + kc * 32 + quad * 8];
        bf16x8 b3 = *(const bf16x8*)&wbf[(3 * 16 + l16) * XPAD + kc * 32 + quad * 8];
        acc0 = __builtin_amdgcn_mfma_f32_16x16x32_bf16(a, b0, acc0, 0, 0, 0);
        acc1 = __builtin_amdgcn_mfma_f32_16x16x32_bf16(a, b1, acc1, 0, 0, 0);
        acc2 = __builtin_amdgcn_mfma_f32_16x16x32_bf16(a, b2, acc2, 0, 0, 0);
        acc3 = __builtin_amdgcn_mfma_f32_16x16x32_bf16(a, b3, acc3, 0, 0, 0);
    }

#pragma unroll
    for (int r = 0; r < 4; ++r) {
        int node = node0 + wv * 16 + quad * 4 + r;
        if (node < n) {
            size_t base = (size_t)node * OUT_C + l16;
            y[base + 0]  = f2fp8(acc0[r]);
            y[base + 16] = f2fp8(acc1[r]);
            y[base + 32] = f2fp8(acc2[r]);
            y[base + 48] = f2fp8(acc3[r]);
        }
    }
}

// ================= count (+ first half of linear), interleaved 2:1 =================
// blockIdx%3 in {0,1} -> count block: atomicAdd in-degree, record the returned
//   within-node slot (eidx) so fill needs no second atomic. count is
//   atomic-latency-bound (~5% BW/VALU), so the interleaved linear blocks ride
//   on idle resources.
// blockIdx%3 == 2     -> linear block for groups [0, lin_half).
__global__ void count_linear_kernel(const int* __restrict__ col, int* __restrict__ cnt,
                                    unsigned short* __restrict__ eidx,
                                    unsigned* __restrict__ csr, int e,
                                    const float* __restrict__ x, const float* __restrict__ W,
                                    unsigned char* __restrict__ y, int n, int lin_half) {
    __shared__ unsigned short wbf[64 * XPAD];
    int g = blockIdx.x / 3;
    int r3 = blockIdx.x - g * 3;
    if (r3 != 2) {
        int i = (g * 2 + r3) * 256 + threadIdx.x;
        if (i < 16) csr[e + i] = 0u;   // tail zeroing for unpredicated gather loads
        if (i < e) {
            int slot = atomicAdd(&cnt[col[i]], 1);
            eidx[i] = (unsigned short)slot;
        }
        return;
    }
    if (g >= lin_half) return;
    linear_block(g, threadIdx.x, x, W, y, n, wbf);
}

// per-512-block sums
__global__ void scan_pass1_kernel(const int* __restrict__ cnt, int* __restrict__ partials, int n) {
    __shared__ int s[SCAN_B];
    int i = blockIdx.x * SCAN_B + threadIdx.x;
    int v = (i < n) ? cnt[i] : 0;
    s[threadIdx.x] = v;
    __syncthreads();
    for (int off = SCAN_B / 2; off > 0; off >>= 1) {
        if (threadIdx.x < off) s[threadIdx.x] += s[threadIdx.x + off];
        __syncthreads();
    }
    if (threadIdx.x == 0) partials[blockIdx.x] = s[0];
}

// fused scan2+scan3: every block redundantly scans the partials (nparts<=512),
// then scans its own 512 cnt elements; writes row_start/dinv (+total).
__global__ void scan23_kernel(const int* __restrict__ cnt, const int* __restrict__ partials,
                              int* __restrict__ row_start, float* __restrict__ dinv,
                              int n, int nparts) {
    __shared__ int ps[SCAN_B];
    __shared__ int es[SCAN_B];
    int t = threadIdx.x;

    int pv = (t < nparts) ? partials[t] : 0;
    ps[t] = pv;
    __syncthreads();
    int run = pv;
    for (int off = 1; off < SCAN_B; off <<= 1) {
        int tmp = (t >= off) ? ps[t - off] : 0;
        __syncthreads();
        run += tmp;
        ps[t] = run;
        __syncthreads();
    }
    int total = ps[nparts - 1];
    __syncthreads();
    ps[t] = run - pv;   // exclusive
    __syncthreads();
    int block_off = ps[blockIdx.x];

    int i = blockIdx.x * SCAN_B + t;
    int v = (i < n) ? cnt[i] : 0;
    es[t] = v;
    __syncthreads();
    int erun = v;
    for (int off = 1; off < SCAN_B; off <<= 1) {
        int tmp = (t >= off) ? es[t - off] : 0;
        __syncthreads();
        erun += tmp;
        es[t] = erun;
        __syncthreads();
    }
    if (i < n) {
        int start = block_off + erun - v;   // exclusive
        row_start[i] = start;
        dinv[i] = rsqrtf((float)v + 1.0f);
    }
    if (blockIdx.x == 0 && t == 0) row_start[n] = total;
}

// ================= fill (+ second half of linear), interleaved 2:1 =================
// blockIdx%3 in {0,1} -> fill block (atomic-free: pos = row_start[c]+eidx[i]).
//   Entry stores dinv[src] only (gather multiplies by dinv[dst]).
// blockIdx%3 == 2     -> linear block for groups [lin_half, nb_lin).
__global__ void fill_linear_kernel(const int* __restrict__ row, const int* __restrict__ col,
                                   const float* __restrict__ dinv,
                                   const int* __restrict__ row_start,
                                   const unsigned short* __restrict__ eidx,
                                   unsigned* __restrict__ csr, int e,
                                   const float* __restrict__ x, const float* __restrict__ W,
                                   unsigned char* __restrict__ y, int n,
                                   int lin_half, int nb_lin) {
    __shared__ unsigned short wbf[64 * XPAD];

    int g = blockIdx.x / 3;
    int r3 = blockIdx.x - g * 3;
    if (r3 != 2) {
        int i = (g * 2 + r3) * 256 + threadIdx.x;
        if (i < e) {
            int r = row[i];
            int c = col[i];
            int pos = row_start[c] + (int)eidx[i];
            csr[pos] = ((unsigned)r << 15) | (unsigned)f2bf(dinv[r]);
        }
        return;
    }
    int gl = lin_half + g;
    if (gl >= nb_lin) return;
    linear_block(gl, threadIdx.x, x, W, y, n, wbf);
}

// ================= gather hop: 16 lanes per node, fp8 rows, 4 nodes per wave =================
// Row = 64 fp8 ch = 64B; lane c (0..15) loads ONE dword = channels 4c..4c+3
// (16 lanes x 4B = 64B coalesced). Decode via HW v_cvt_f32_fp8. csr loads
// unpredicated (zeroed tail), ENTRY masked: invalid slot -> p=0 -> w=+0.0 AND
// src=node 0 (hot line). Accumulation bank order unchanged.

#define GACC(EA, EB, EC, ED, w, v) \
    EA += (w) * __builtin_amdgcn_cvt_f32_fp8((int)(v), 0); \
    EB += (w) * __builtin_amdgcn_cvt_f32_fp8((int)(v), 1); \
    EC += (w) * __builtin_amdgcn_cvt_f32_fp8((int)(v), 2); \
    ED += (w) * __builtin_amdgcn_cvt_f32_fp8((int)(v), 3);

template <bool FINAL>
__global__ void gather_kernel(const unsigned char* __restrict__ src,
                              unsigned char* __restrict__ dst_fp8,
                              float* __restrict__ dst_f32,
                              const int* __restrict__ row_start, const unsigned* __restrict__ csr,
                              const float* __restrict__ dinv, const float* __restrict__ bias,
                              int n) {
    int node = blockIdx.x * (blockDim.x >> 4) + (threadIdx.x >> 4);
    if (node >= n) return;
    int c = threadIdx.x & 15;                // dword index: channels 4c..4c+3
    const unsigned* srcp = (const unsigned*)src;

    int beg = row_start[node];
    int end = row_start[node + 1];

    // self-loop
    unsigned pv = srcp[(size_t)node * 16 + c];
    float s = dinv[node];
    float ss = s * s;

    float e0a = 0.f, e0b = 0.f, e0c = 0.f, e0d = 0.f;
    float e1a = 0.f, e1b = 0.f, e1c = 0.f, e1d = 0.f;
    float e2a = 0.f, e2b = 0.f, e2c = 0.f, e2d = 0.f;
    float e3a = 0.f, e3b = 0.f, e3c = 0.f, e3d = 0.f;
    GACC(e0a, e0b, e0c, e0d, ss, pv)

    for (int j0 = beg; j0 < end; j0 += 16) {
        unsigned t0 = csr[j0];
        unsigned t1 = csr[j0 + 1];
        unsigned t2 = csr[j0 + 2];
        unsigned t3 = csr[j0 + 3];
        unsigned t4 = csr[j0 + 4];
        unsigned t5 = csr[j0 + 5];
        unsigned t6 = csr[j0 + 6];
        unsigned t7 = csr[j0 + 7];
        unsigned t8 = csr[j0 + 8];
        unsigned t9 = csr[j0 + 9];
        unsigned ta = csr[j0 + 10];
        unsigned tb = csr[j0 + 11];
        unsigned tc = csr[j0 + 12];
        unsigned td = csr[j0 + 13];
        unsigned te = csr[j0 + 14];
        unsigned tf = csr[j0 + 15];
        unsigned p0 = (j0 + 0  < end) ? t0 : 0u;
        unsigned p1 = (j0 + 1  < end) ? t1 : 0u;
        unsigned p2 = (j0 + 2  < end) ? t2 : 0u;
        unsigned p3 = (j0 + 3  < end) ? t3 : 0u;
        unsigned p4 = (j0 + 4  < end) ? t4 : 0u;
        unsigned p5 = (j0 + 5  < end) ? t5 : 0u;
        unsigned p6 = (j0 + 6  < end) ? t6 : 0u;
        unsigned p7 = (j0 + 7  < end) ? t7 : 0u;
        unsigned p8 = (j0 + 8  < end) ? t8 : 0u;
        unsigned p9 = (j0 + 9  < end) ? t9 : 0u;
        unsigned pa = (j0 + 10 < end) ? ta : 0u;
        unsigned pb = (j0 + 11 < end) ? tb : 0u;
        unsigned pc = (j0 + 12 < end) ? tc : 0u;
        unsigned pd = (j0 + 13 < end) ? td : 0u;
        unsigned pe = (j0 + 14 < end) ? te : 0u;
        unsigned pf = (j0 + 15 < end) ? tf : 0u;
        unsigned v0 = srcp[(size_t)(p0 >> 15) * 16 + c];
        unsigned v1 = srcp[(size_t)(p1 >> 15) * 16 + c];
        unsigned v2 = srcp[(size_t)(p2 >> 15) * 16 + c];
        unsigned v3 = srcp[(size_t)(p3 >> 15) * 16 + c];
        unsigned v4 = srcp[(size_t)(p4 >> 15) * 16 + c];
        unsigned v5 = srcp[(size_t)(p5 >> 15) * 16 + c];
        unsigned v6 = srcp[(size_t)(p6 >> 15) * 16 + c];
        unsigned v7 = srcp[(size_t)(p7 >> 15) * 16 + c];
        unsigned v8 = srcp[(size_t)(p8 >> 15) * 16 + c];
        unsigned v9 = srcp[(size_t)(p9 >> 15) * 16 + c];
        unsigned va = srcp[(size_t)(pa >> 15) * 16 + c];
        unsigned vb = srcp[(size_t)(pb >> 15) * 16 + c];
        unsigned vc = srcp[(size_t)(pc >> 15) * 16 + c];
        unsigned vd = srcp[(size_t)(pd >> 15) * 16 + c];
        unsigned ve = srcp[(size_t)(pe >> 15) * 16 + c];
        unsigned vf = srcp[(size_t)(pf >> 15) * 16 + c];
        float w0 = dec_w(p0) * s, w1 = dec_w(p1) * s, w2 = dec_w(p2) * s, w3 = dec_w(p3) * s;
        float w4 = dec_w(p4) * s, w5 = dec_w(p5) * s, w6 = dec_w(p6) * s, w7 = dec_w(p7) * s;
        float w8 = dec_w(p8) * s, w9 = dec_w(p9) * s, wa = dec_w(pa) * s, wb = dec_w(pb) * s;
        float wc = dec_w(pc) * s, wd = dec_w(pd) * s, we = dec_w(pe) * s, wf = dec_w(pf) * s;
        GACC(e0a, e0b, e0c, e0d, w0, v0)
        GACC(e1a, e1b, e1c, e1d, w1, v1)
        GACC(e2a, e2b, e2c, e2d, w2, v2)
        GACC(e3a, e3b, e3c, e3d, w3, v3)
        GACC(e0a, e0b, e0c, e0d, w4, v4)
        GACC(e1a, e1b, e1c, e1d, w5, v5)
        GACC(e2a, e2b, e2c, e2d, w6, v6)
        GACC(e3a, e3b, e3c, e3d, w7, v7)
        GACC(e0a, e0b, e0c, e0d, w8, v8)
        GACC(e1a, e1b, e1c, e1d, w9, v9)
        GACC(e2a, e2b, e2c, e2d, wa, va)
        GACC(e3a, e3b, e3c, e3d, wb, vb)
        GACC(e0a, e0b, e0c, e0d, wc, vc)
        GACC(e1a, e1b, e1c, e1d, wd, vd)
        GACC(e2a, e2b, e2c, e2d, we, ve)
        GACC(e3a, e3b, e3c, e3d, wf, vf)
    }
    float a0 = (e0a + e1a) + (e2a + e3a);
    float a1 = (e0b + e1b) + (e2b + e3b);
    float a2 = (e0c + e1c) + (e2c + e3c);
    float a3 = (e0d + e1d) + (e2d + e3d);

    if (FINAL) {
        float4 bb = ((const float4*)bias)[c];
        float4 o;
        o.x = 1.0f / (1.0f + __expf(-(a0 + bb.x)));
        o.y = 1.0f / (1.0f + __expf(-(a1 + bb.y)));
        o.z = 1.0f / (1.0f + __expf(-(a2 + bb.z)));
        o.w = 1.0f / (1.0f + __expf(-(a3 + bb.w)));
        ((float4*)dst_f32)[(size_t)node * 16 + c] = o;
    } else {
        unsigned o = (unsigned)__builtin_amdgcn_cvt_pk_fp8_f32(a0, a1, 0, false);
        o = (unsigned)__builtin_amdgcn_cvt_pk_fp8_f32(a2, a3, (int)o, true);
        ((unsigned*)dst_fp8)[(size_t)node * 16 + c] = o;
    }
}

// ================= launch =================

static inline size_t align16(size_t x) { return (x + 15) & ~(size_t)15; }

extern "C" void kernel_launch(void* const* d_in, const int* in_sizes, int n_in,
                              void* d_out, int out_size, void* d_ws, size_t ws_size,
                              hipStream_t stream) {
    const float* x = (const float*)d_in[0];
    const int* edge_index = (const int*)d_in[1];
    const float* W = (const float*)d_in[2];
    const float* b = (const float*)d_in[3];
    float* out = (float*)d_out;

    const int N = N_NODES;
    const int E = in_sizes[1] / 2;

    const int* row = edge_index;        // source
    const int* col = edge_index + E;    // destination

    char* ws = (char*)d_ws;
    size_t off = 0;
    int* cnt = (int*)(ws + off);             off = align16(off + (size_t)N * 4);
    float* dinv = (float*)(ws + off);        off = align16(off + (size_t)N * 4);
    int* row_start = (int*)(ws + off);       off = align16(off + (size_t)(N + 1) * 4);
    int* partials = (int*)(ws + off);        off = align16(off + 512 * 4);
    unsigned* csr = (unsigned*)(ws + off);   off = align16(off + (size_t)(E + 16) * 4);
    unsigned char* y0 = (unsigned char*)(ws + off); off = align16(off + (size_t)N * OUT_C);
    unsigned char* y1 = (unsigned char*)(ws + off); off = align16(off + (size_t)N * OUT_C);
    // eidx lifetime (count -> fill) is disjoint from y1 (gather1 -> gather2): alias.
    unsigned short* eidx = (unsigned short*)y1;   // 1.6MB < 6.4MB

    const int B = 256;
    const int nb_e = (E + B - 1) / B;               // 3125
    const int nb_scan = (N + SCAN_B - 1) / SCAN_B;  // 196
    const int nb_lin = (N + 63) / 64;               // 1563
    const int lin_half = nb_lin / 2;                // 781 linear groups in count phase
    int nbg_c = (nb_e + 1) / 2;                     // 1563 groups of {2 count, 1 linear}
    if (nbg_c < lin_half) nbg_c = lin_half;
    int nbg_f = (nb_e + 1) / 2;                     // 1563 groups of {2 fill, 1 linear}
    if (nbg_f < nb_lin - lin_half) nbg_f = nb_lin - lin_half;

    // ---- count (+ first half of linear) ----
    hipMemsetAsync(cnt, 0, (size_t)N * 4, stream);
    count_linear_kernel<<<3 * nbg_c, B, 0, stream>>>(col, cnt, eidx, csr, E,
                                                     x, W, y0, N, lin_half);
    scan_pass1_kernel<<<nb_scan, SCAN_B, 0, stream>>>(cnt, partials, N);
    scan23_kernel<<<nb_scan, SCAN_B, 0, stream>>>(cnt, partials, row_start, dinv, N, nb_scan);

    // ---- fill (atomic-free) + second half of linear ----
    fill_linear_kernel<<<3 * nbg_f, B, 0, stream>>>(row, col, dinv, row_start, eidx, csr, E,
                                                    x, W, y0, N, lin_half, nb_lin);

    // ---- hop 1 (16 nodes per 256-thread block) ----
    gather_kernel<false><<<(N + 15) / 16, B, 0, stream>>>(y0, y1, nullptr, row_start, csr, dinv, b, N);

    // ---- hop 2 + bias + sigmoid ----
    gather_kernel<true><<<(N + 15) / 16, B, 0, stream>>>(y1, nullptr, out, row_start, csr, dinv, b, N);
}